// Round 15
// baseline (145.144 us; speedup 1.0000x reference)
//
#include <hip/hip_runtime.h>

#define NN 100000
#define NE 1600000

#define NRANGE 256
#define RDST 391                          // ceil(NN/NRANGE); 256*391 = 100096
#define CAP 6800                          // per-range bin capacity (mean 6256, ~7 sigma)
#define EPB_A 4096
#define NCHA ((NE + EPB_A - 1) / EPB_A)   // 391 chunks
#define GEMM_BLK 782                      // ceil(NN/128)

typedef __attribute__((ext_vector_type(8))) __bf16 bf16x8;
typedef __attribute__((ext_vector_type(4))) float  f32x4;

static __device__ __forceinline__ unsigned f2bf(float f) {
    unsigned u = __float_as_uint(f);
    return (u + 0x7fffu + ((u >> 16) & 1u)) >> 16;   // RNE
}
static __device__ __forceinline__ float bf2f(unsigned b) {
    return __uint_as_float(b << 16);
}

union PkA { unsigned u[4]; bf16x8 b; };

// ---------------------------------------------------------------------------
// kA: fused independent phases.
//   block 0       : B-panel prep ([W|Wa|0] -> split-bf16 fragment order)
//   blocks 1..391 : ka_bin chunk binning (4096 edges/chunk)
// ---------------------------------------------------------------------------
__global__ __launch_bounds__(256) void kA_prep_bin(
    const float* __restrict__ W, const float* __restrict__ a,
    uint4* __restrict__ B0g, uint4* __restrict__ B1g,
    const int* __restrict__ ei, int* __restrict__ rangeRes,
    unsigned* __restrict__ bins)
{
    __shared__ float sWa[1024];
    __shared__ int cnt[NRANGE], base[NRANGE], cur[NRANGE];
    const int t = threadIdx.x;

    if (blockIdx.x == 0) {
        // ---- kprep ----
        for (int e = t; e < 1024; e += 256) {
            int k = e >> 3, j = e & 7, q = j >> 1, s = j & 1;
            float sum = 0.f;
            #pragma unroll
            for (int c = 0; c < 32; ++c)
                sum = fmaf(W[k * 128 + q * 32 + c], a[q * 64 + s * 32 + c], sum);
            sWa[e] = sum;
        }
        __syncthreads();
        #pragma unroll
        for (int it = 0; it < 9; ++it) {
            int f  = it * 256 + t;         // 0..2303
            int l  = f & 63;
            int tk = (f >> 6) & 3;
            int tn = f >> 8;
            int col = tn * 16 + (l & 15);
            int kk  = tk * 32 + ((l >> 4) << 3);
            unsigned hb[8], lb[8];
            #pragma unroll
            for (int j = 0; j < 8; ++j) {
                float w;
                if (col < 128)       w = W[(kk + j) * 128 + col];
                else if (col < 136)  w = sWa[(kk + j) * 8 + (col - 128)];
                else                 w = 0.f;
                hb[j] = f2bf(w);
                lb[j] = f2bf(w - bf2f(hb[j]));
            }
            B0g[f] = make_uint4(hb[0] | (hb[1] << 16), hb[2] | (hb[3] << 16),
                                hb[4] | (hb[5] << 16), hb[6] | (hb[7] << 16));
            B1g[f] = make_uint4(lb[0] | (lb[1] << 16), lb[2] | (lb[3] << 16),
                                lb[4] | (lb[5] << 16), lb[6] | (lb[7] << 16));
        }
        return;
    }

    // ---- ka_bin ----
    const int c  = blockIdx.x - 1;
    const int b0 = c * EPB_A;
    const int b1 = min(NE, b0 + EPB_A);

    cnt[t] = 0;
    __syncthreads();
    for (int i = b0 + t; i < b1; i += 256)
        atomicAdd(&cnt[ei[NE + i] / RDST], 1);
    __syncthreads();
    base[t] = atomicAdd(&rangeRes[t * 16], cnt[t]) + t * CAP;
    cur[t] = 0;
    __syncthreads();
    for (int i = b0 + t; i < b1; i += 256) {
        int s = ei[i], d = ei[NE + i];
        int r = d / RDST;
        unsigned dloc = (unsigned)(d - r * RDST);
        int off = atomicAdd(&cur[r], 1);
        bins[base[r] + off] = (dloc << 17) | (unsigned)s;
    }
}

// ---------------------------------------------------------------------------
// kB: fused independent phases.
//   blocks 0..781    : k1 GEMM, 128 rows/block, B fragments read DIRECTLY
//                      from global (block-invariant addresses -> L1/L2
//                      broadcast; no LDS staging, no barriers, 16 KB LDS).
//   blocks 782..1037 : kb_build (R13 version; LDS aliased into scratch)
// ---------------------------------------------------------------------------
__global__ __launch_bounds__(256) void kB_gemm_build(
    const float* __restrict__ X, const uint4* __restrict__ B0g,
    const uint4* __restrict__ B1g, unsigned short* __restrict__ h16,
    float* __restrict__ asrc, float* __restrict__ adst,
    const int* __restrict__ rangeRes, const unsigned* __restrict__ bins,
    int* __restrict__ csr_src, int* __restrict__ cursor)
{
    __shared__ unsigned short scratch[4 * 2048];   // 16 KB
    const int tid = threadIdx.x;

    if (blockIdx.x < GEMM_BLK) {
        const int w = tid >> 6;
        const int l = tid & 63;
        const int r0 = blockIdx.x * 128 + w * 16 + (l & 15);  // mt=0 A row
        const float* xr0 = X + (size_t)min(r0,      NN - 1) * 128 + ((l >> 4) << 3);
        const float* xr1 = X + (size_t)min(r0 + 64, NN - 1) * 128 + ((l >> 4) << 3);
        const bf16x8* Bh = (const bf16x8*)B0g;
        const bf16x8* Bl = (const bf16x8*)B1g;

        f32x4 acc[2][9];
        #pragma unroll
        for (int m = 0; m < 2; ++m)
            #pragma unroll
            for (int t = 0; t < 9; ++t) acc[m][t] = (f32x4){0.f, 0.f, 0.f, 0.f};

        #pragma unroll
        for (int tk = 0; tk < 4; ++tk) {
            float4 xa0 = *(const float4*)(xr0 + tk * 32);
            float4 xb0 = *(const float4*)(xr0 + tk * 32 + 4);
            float4 xa1 = *(const float4*)(xr1 + tk * 32);
            float4 xb1 = *(const float4*)(xr1 + tk * 32 + 4);
            PkA p0, p1;
            p0.u[0] = f2bf(xa0.x) | (f2bf(xa0.y) << 16);
            p0.u[1] = f2bf(xa0.z) | (f2bf(xa0.w) << 16);
            p0.u[2] = f2bf(xb0.x) | (f2bf(xb0.y) << 16);
            p0.u[3] = f2bf(xb0.z) | (f2bf(xb0.w) << 16);
            p1.u[0] = f2bf(xa1.x) | (f2bf(xa1.y) << 16);
            p1.u[1] = f2bf(xa1.z) | (f2bf(xa1.w) << 16);
            p1.u[2] = f2bf(xb1.x) | (f2bf(xb1.y) << 16);
            p1.u[3] = f2bf(xb1.z) | (f2bf(xb1.w) << 16);
            #pragma unroll
            for (int tn = 0; tn < 9; ++tn) {
                int fi = ((tn << 2) + tk) * 64 + l;
                bf16x8 bh = Bh[fi];
                bf16x8 bl = Bl[fi];
                acc[0][tn] = __builtin_amdgcn_mfma_f32_16x16x32_bf16(p0.b, bh, acc[0][tn], 0, 0, 0);
                acc[0][tn] = __builtin_amdgcn_mfma_f32_16x16x32_bf16(p0.b, bl, acc[0][tn], 0, 0, 0);
                acc[1][tn] = __builtin_amdgcn_mfma_f32_16x16x32_bf16(p1.b, bh, acc[1][tn], 0, 0, 0);
                acc[1][tn] = __builtin_amdgcn_mfma_f32_16x16x32_bf16(p1.b, bl, acc[1][tn], 0, 0, 0);
            }
        }

        // ---- epilogue: wave-private LDS transpose scratch, no barriers ----
        const int g = l >> 4;
        unsigned short* hs = scratch + w * 2048;   // 16x128 bf16 (4 KB)
        #pragma unroll
        for (int mt = 0; mt < 2; ++mt) {
            const int rowbase = blockIdx.x * 128 + mt * 64 + w * 16;
            #pragma unroll
            for (int tn = 0; tn < 8; ++tn) {
                #pragma unroll
                for (int r = 0; r < 4; ++r)
                    hs[((g << 2) + r) * 128 + (tn << 4) + (l & 15)] =
                        (unsigned short)f2bf(acc[mt][tn][r]);
            }
            if ((l & 15) < 8) {
                int j = l & 15, q = j >> 1, s = j & 1;
                float* dp = s ? adst : asrc;
                #pragma unroll
                for (int r = 0; r < 4; ++r) {
                    int rr = rowbase + (g << 2) + r;
                    if (rr < NN) dp[rr * 4 + q] = acc[mt][8][r];
                }
            }
            if (rowbase < NN) {
                const uint4* sp = (const uint4*)hs;
                uint4* dp = (uint4*)(h16 + (size_t)rowbase * 128);
                #pragma unroll
                for (int i = 0; i < 4; ++i) dp[i * 64 + l] = sp[i * 64 + l];
            }
        }
        return;
    }

    // ---- kb_build (R13 version; LDS aliased into scratch) ----
    int* lenS = (int*)scratch;       // [256]
    int* hist = lenS + NRANGE;       // [512]
    int* cur  = hist + 512;          // [391]
    const int r = blockIdx.x - GEMM_BLK;
    const int t = tid;

    lenS[t] = rangeRes[t * 16];
    __syncthreads();
    for (int off = 1; off < NRANGE; off <<= 1) {
        int v = (t >= off) ? lenS[t - off] : 0;
        __syncthreads();
        lenS[t] += v;
        __syncthreads();
    }
    const int rangeOff = r ? lenS[r - 1] : 0;
    const int n = lenS[r] - rangeOff;
    const int lo = r * RDST;
    const int nd = min(RDST, NN - lo);

    hist[t] = 0; hist[t + 256] = 0;
    __syncthreads();
    const unsigned* bp = bins + (size_t)r * CAP;
    for (int i = t; i < n; i += 256)
        atomicAdd(&hist[bp[i] >> 17], 1);
    __syncthreads();
    for (int off = 1; off < 512; off <<= 1) {
        int i0 = t, i1 = t + 256;
        int v0 = (i0 >= off) ? hist[i0 - off] : 0;
        int v1 = (i1 >= off) ? hist[i1 - off] : 0;
        __syncthreads();
        hist[i0] += v0; hist[i1] += v1;
        __syncthreads();
    }
    for (int b = t; b < RDST; b += 256) cur[b] = b ? hist[b - 1] : 0;
    __syncthreads();
    for (int i = t; i < n; i += 256) {
        unsigned v = bp[i];
        int pos = atomicAdd(&cur[v >> 17], 1);
        csr_src[rangeOff + pos] = (int)(v & 0x1FFFFu);
    }
    __syncthreads();
    for (int b = t; b < nd; b += 256) cursor[lo + b] = rangeOff + cur[b];
}

// ---------------------------------------------------------------------------
// k4: one wave per dst node; four 16-lane groups, software-pipelined 4-deep.
// ---------------------------------------------------------------------------
__global__ __launch_bounds__(256) void k4_agg(
    const int* __restrict__ cursor, const int* __restrict__ csr_src,
    const float* __restrict__ asrc, const float* __restrict__ adst,
    const unsigned short* __restrict__ h16, float* __restrict__ out)
{
    int wid = (blockIdx.x * 256 + threadIdx.x) >> 6;
    if (wid >= NN) return;
    int l = threadIdx.x & 63;
    int g = l >> 4;           // edge subgroup 0..3
    int cidx = l & 15;        // col granule: cols cidx*8 .. cidx*8+7
    int head = cidx >> 2;

    int end = cursor[wid];
    int beg = wid ? cursor[wid - 1] : 0;

    float ad = adst[(size_t)wid * 4 + head];

    float acc[8];
    #pragma unroll
    for (int c = 0; c < 8; ++c) acc[c] = 0.f;
    float sum = 0.f;

    int i = beg + g;
    if (i < end) {
        const int last = end - 1;
        int s0 = csr_src[i];
        int s1 = csr_src[min(i + 4,  last)];
        int s2 = csr_src[min(i + 8,  last)];
        int s3 = csr_src[min(i + 12, last)];
        do {
            int i2 = i + 16;
            int t0 = csr_src[min(i2,      last)];
            int t1 = csr_src[min(i2 + 4,  last)];
            int t2 = csr_src[min(i2 + 8,  last)];
            int t3 = csr_src[min(i2 + 12, last)];

            float a0 = asrc[(size_t)s0 * 4 + head];
            uint4 h0 = *(const uint4*)(h16 + (size_t)s0 * 128 + cidx * 8);
            float a1 = asrc[(size_t)s1 * 4 + head];
            uint4 h1 = *(const uint4*)(h16 + (size_t)s1 * 128 + cidx * 8);
            float a2 = asrc[(size_t)s2 * 4 + head];
            uint4 h2 = *(const uint4*)(h16 + (size_t)s2 * 128 + cidx * 8);
            float a3 = asrc[(size_t)s3 * 4 + head];
            uint4 h3 = *(const uint4*)(h16 + (size_t)s3 * 128 + cidx * 8);

            float sc0 = a0 + ad; sc0 = sc0 >= 0.f ? sc0 : 0.2f * sc0;
            float sc1 = a1 + ad; sc1 = sc1 >= 0.f ? sc1 : 0.2f * sc1;
            float sc2 = a2 + ad; sc2 = sc2 >= 0.f ? sc2 : 0.2f * sc2;
            float sc3 = a3 + ad; sc3 = sc3 >= 0.f ? sc3 : 0.2f * sc3;
            float w0 = __expf(sc0);
            float w1 = (i + 4  <= last) ? __expf(sc1) : 0.f;
            float w2 = (i + 8  <= last) ? __expf(sc2) : 0.f;
            float w3 = (i + 12 <= last) ? __expf(sc3) : 0.f;
            sum += (w0 + w1) + (w2 + w3);

            acc[0] = fmaf(w0, __uint_as_float(h0.x << 16),         acc[0]);
            acc[1] = fmaf(w0, __uint_as_float(h0.x & 0xffff0000u), acc[1]);
            acc[2] = fmaf(w0, __uint_as_float(h0.y << 16),         acc[2]);
            acc[3] = fmaf(w0, __uint_as_float(h0.y & 0xffff0000u), acc[3]);
            acc[4] = fmaf(w0, __uint_as_float(h0.z << 16),         acc[4]);
            acc[5] = fmaf(w0, __uint_as_float(h0.z & 0xffff0000u), acc[5]);
            acc[6] = fmaf(w0, __uint_as_float(h0.w << 16),         acc[6]);
            acc[7] = fmaf(w0, __uint_as_float(h0.w & 0xffff0000u), acc[7]);

            acc[0] = fmaf(w1, __uint_as_float(h1.x << 16),         acc[0]);
            acc[1] = fmaf(w1, __uint_as_float(h1.x & 0xffff0000u), acc[1]);
            acc[2] = fmaf(w1, __uint_as_float(h1.y << 16),         acc[2]);
            acc[3] = fmaf(w1, __uint_as_float(h1.y & 0xffff0000u), acc[3]);
            acc[4] = fmaf(w1, __uint_as_float(h1.z << 16),         acc[4]);
            acc[5] = fmaf(w1, __uint_as_float(h1.z & 0xffff0000u), acc[5]);
            acc[6] = fmaf(w1, __uint_as_float(h1.w << 16),         acc[6]);
            acc[7] = fmaf(w1, __uint_as_float(h1.w & 0xffff0000u), acc[7]);

            acc[0] = fmaf(w2, __uint_as_float(h2.x << 16),         acc[0]);
            acc[1] = fmaf(w2, __uint_as_float(h2.x & 0xffff0000u), acc[1]);
            acc[2] = fmaf(w2, __uint_as_float(h2.y << 16),         acc[2]);
            acc[3] = fmaf(w2, __uint_as_float(h2.y & 0xffff0000u), acc[3]);
            acc[4] = fmaf(w2, __uint_as_float(h2.z << 16),         acc[4]);
            acc[5] = fmaf(w2, __uint_as_float(h2.z & 0xffff0000u), acc[5]);
            acc[6] = fmaf(w2, __uint_as_float(h2.w << 16),         acc[6]);
            acc[7] = fmaf(w2, __uint_as_float(h2.w & 0xffff0000u), acc[7]);

            acc[0] = fmaf(w3, __uint_as_float(h3.x << 16),         acc[0]);
            acc[1] = fmaf(w3, __uint_as_float(h3.x & 0xffff0000u), acc[1]);
            acc[2] = fmaf(w3, __uint_as_float(h3.y << 16),         acc[2]);
            acc[3] = fmaf(w3, __uint_as_float(h3.y & 0xffff0000u), acc[3]);
            acc[4] = fmaf(w3, __uint_as_float(h3.z << 16),         acc[4]);
            acc[5] = fmaf(w3, __uint_as_float(h3.z & 0xffff0000u), acc[5]);
            acc[6] = fmaf(w3, __uint_as_float(h3.w << 16),         acc[6]);
            acc[7] = fmaf(w3, __uint_as_float(h3.w & 0xffff0000u), acc[7]);

            s0 = t0; s1 = t1; s2 = t2; s3 = t3; i = i2;
        } while (i < end);
    }

    #pragma unroll
    for (int c = 0; c < 8; ++c) {
        acc[c] += __shfl_xor(acc[c], 16);
        acc[c] += __shfl_xor(acc[c], 32);
    }
    sum += __shfl_xor(sum, 16);
    sum += __shfl_xor(sum, 32);

    if (g == 0) {
        float rs = 1.0f / (sum + 1e-16f);
        f32x4* ob = (f32x4*)(out + (size_t)wid * 128 + cidx * 8);
        f32x4 v0 = {acc[0] * rs, acc[1] * rs, acc[2] * rs, acc[3] * rs};
        f32x4 v1 = {acc[4] * rs, acc[5] * rs, acc[6] * rs, acc[7] * rs};
        __builtin_nontemporal_store(v0, ob);
        __builtin_nontemporal_store(v1, ob + 1);
    }
}

// ---------------------------------------------------------------------------
extern "C" void kernel_launch(void* const* d_in, const int* in_sizes, int n_in,
                              void* d_out, int out_size, void* d_ws, size_t ws_size,
                              hipStream_t stream)
{
    const float* X  = (const float*)d_in[0];
    const int*   ei = (const int*)d_in[1];
    const float* W  = (const float*)d_in[2];
    const float* a  = (const float*)d_in[3];
    float* out = (float*)d_out;

    // workspace layout (4-byte elements), total ~43 MB
    unsigned short* h16 = (unsigned short*)d_ws;          // NN*128 bf16 = 6.4M elems
    float* asrc     = (float*)d_ws + 6400000;             // NN*4
    float* adst     = asrc + 400000;                      // NN*4
    int*   csr_src  = (int*)(adst + 400000);              // NE
    int*   cursor   = csr_src + 1600000;                  // NN
    int*   rangeRes = cursor + 100000;                    // NRANGE*16 (padded)
    uint4* B0g      = (uint4*)(rangeRes + NRANGE * 16);   // 2304 uint4 = 36 KB
    uint4* B1g      = B0g + 2304;                         // 36 KB
    unsigned* bins  = (unsigned*)(B1g + 2304);            // NRANGE*CAP = 7 MB

    hipMemsetAsync(rangeRes, 0, NRANGE * 16 * sizeof(int), stream);

    kA_prep_bin<<<1 + NCHA, 256, 0, stream>>>(W, a, B0g, B1g, ei, rangeRes, bins);
    kB_gemm_build<<<GEMM_BLK + NRANGE, 256, 0, stream>>>(X, B0g, B1g, h16,
                                                         asrc, adst, rangeRes,
                                                         bins, csr_src, cursor);
    k4_agg<<<(NN * 64 + 255) / 256, 256, 0, stream>>>(cursor, csr_src,
                                                      asrc, adst, h16, out);
}

// Round 16
// 138.739 us; speedup vs baseline: 1.0462x; 1.0462x over previous
//
#include <hip/hip_runtime.h>

#define NN 100000
#define NE 1600000

#define NRANGE 256
#define RDST 391                          // ceil(NN/NRANGE); 256*391 = 100096
#define CAP 6800                          // per-range bin capacity (mean 6256, ~7 sigma)
#define EPB_A 4096
#define NCHA ((NE + EPB_A - 1) / EPB_A)   // 391 chunks
#define GEMM_BLK 782                      // ceil(NN/128)

typedef __attribute__((ext_vector_type(8))) __bf16 bf16x8;
typedef __attribute__((ext_vector_type(4))) float  f32x4;

static __device__ __forceinline__ unsigned f2bf(float f) {
    unsigned u = __float_as_uint(f);
    return (u + 0x7fffu + ((u >> 16) & 1u)) >> 16;   // RNE
}
static __device__ __forceinline__ float bf2f(unsigned b) {
    return __uint_as_float(b << 16);
}

union PkA { unsigned u[4]; bf16x8 b; __bf16 e[8]; };

// ---------------------------------------------------------------------------
// kA: fused independent phases.
//   block 0       : B-panel prep ([W|Wa|0] -> split-bf16 fragment order)
//   blocks 1..391 : ka_bin chunk binning (4096 edges/chunk)
// ---------------------------------------------------------------------------
__global__ __launch_bounds__(256) void kA_prep_bin(
    const float* __restrict__ W, const float* __restrict__ a,
    uint4* __restrict__ B0g, uint4* __restrict__ B1g,
    const int* __restrict__ ei, int* __restrict__ rangeRes,
    unsigned* __restrict__ bins)
{
    __shared__ float sWa[1024];
    __shared__ int cnt[NRANGE], base[NRANGE], cur[NRANGE];
    const int t = threadIdx.x;

    if (blockIdx.x == 0) {
        // ---- kprep ----
        for (int e = t; e < 1024; e += 256) {
            int k = e >> 3, j = e & 7, q = j >> 1, s = j & 1;
            float sum = 0.f;
            #pragma unroll
            for (int c = 0; c < 32; ++c)
                sum = fmaf(W[k * 128 + q * 32 + c], a[q * 64 + s * 32 + c], sum);
            sWa[e] = sum;
        }
        __syncthreads();
        #pragma unroll
        for (int it = 0; it < 9; ++it) {
            int f  = it * 256 + t;         // 0..2303
            int l  = f & 63;
            int tk = (f >> 6) & 3;
            int tn = f >> 8;
            int col = tn * 16 + (l & 15);
            int kk  = tk * 32 + ((l >> 4) << 3);
            unsigned hb[8], lb[8];
            #pragma unroll
            for (int j = 0; j < 8; ++j) {
                float w;
                if (col < 128)       w = W[(kk + j) * 128 + col];
                else if (col < 136)  w = sWa[(kk + j) * 8 + (col - 128)];
                else                 w = 0.f;
                hb[j] = f2bf(w);
                lb[j] = f2bf(w - bf2f(hb[j]));
            }
            B0g[f] = make_uint4(hb[0] | (hb[1] << 16), hb[2] | (hb[3] << 16),
                                hb[4] | (hb[5] << 16), hb[6] | (hb[7] << 16));
            B1g[f] = make_uint4(lb[0] | (lb[1] << 16), lb[2] | (lb[3] << 16),
                                lb[4] | (lb[5] << 16), lb[6] | (lb[7] << 16));
        }
        return;
    }

    // ---- ka_bin ----
    const int c  = blockIdx.x - 1;
    const int b0 = c * EPB_A;
    const int b1 = min(NE, b0 + EPB_A);

    cnt[t] = 0;
    __syncthreads();
    for (int i = b0 + t; i < b1; i += 256)
        atomicAdd(&cnt[ei[NE + i] / RDST], 1);
    __syncthreads();
    base[t] = atomicAdd(&rangeRes[t * 16], cnt[t]) + t * CAP;
    cur[t] = 0;
    __syncthreads();
    for (int i = b0 + t; i < b1; i += 256) {
        int s = ei[i], d = ei[NE + i];
        int r = d / RDST;
        unsigned dloc = (unsigned)(d - r * RDST);
        int off = atomicAdd(&cur[r], 1);
        bins[base[r] + off] = (dloc << 17) | (unsigned)s;
    }
}

// ---------------------------------------------------------------------------
// kB: fused independent phases (R13 structure).
//   blocks 0..781    : k1 GEMM, 128 rows/block, LDS-staged B panels;
//                      A-packing + epilogue use HW bf16 casts
//                      (v_cvt_pk_bf16_f32) instead of manual RNE bit-ops.
//   blocks 782..1037 : kb_build (LDS aliased into B0 staging buffer)
// ---------------------------------------------------------------------------
__global__ __launch_bounds__(256) void kB_gemm_build(
    const float* __restrict__ X, const uint4* __restrict__ B0g,
    const uint4* __restrict__ B1g, unsigned short* __restrict__ h16,
    float* __restrict__ asrc, float* __restrict__ adst,
    const int* __restrict__ rangeRes, const unsigned* __restrict__ bins,
    int* __restrict__ csr_src, int* __restrict__ cursor)
{
    __shared__ unsigned short B0[9 * 4 * 64 * 8];   // 36 KB  hi
    __shared__ unsigned short B1[9 * 4 * 64 * 8];   // 36 KB  lo
    const int tid = threadIdx.x;

    if (blockIdx.x < GEMM_BLK) {
        // ---- stage B (coalesced copy of pre-converted panels) ----
        {
            uint4* s0 = (uint4*)B0;
            uint4* s1 = (uint4*)B1;
            #pragma unroll
            for (int it = 0; it < 9; ++it) {
                s0[it * 256 + tid] = B0g[it * 256 + tid];
                s1[it * 256 + tid] = B1g[it * 256 + tid];
            }
        }
        __syncthreads();

        const int w = tid >> 6;
        const int l = tid & 63;
        const int r0 = blockIdx.x * 128 + w * 16 + (l & 15);  // mt=0 A row
        const float* xr0 = X + (size_t)min(r0,      NN - 1) * 128 + ((l >> 4) << 3);
        const float* xr1 = X + (size_t)min(r0 + 64, NN - 1) * 128 + ((l >> 4) << 3);

        f32x4 acc[2][9];
        #pragma unroll
        for (int m = 0; m < 2; ++m)
            #pragma unroll
            for (int t = 0; t < 9; ++t) acc[m][t] = (f32x4){0.f, 0.f, 0.f, 0.f};

        #pragma unroll
        for (int tk = 0; tk < 4; ++tk) {
            float4 xa0 = *(const float4*)(xr0 + tk * 32);
            float4 xb0 = *(const float4*)(xr0 + tk * 32 + 4);
            float4 xa1 = *(const float4*)(xr1 + tk * 32);
            float4 xb1 = *(const float4*)(xr1 + tk * 32 + 4);
            PkA p0, p1;
            p0.e[0] = (__bf16)xa0.x; p0.e[1] = (__bf16)xa0.y;
            p0.e[2] = (__bf16)xa0.z; p0.e[3] = (__bf16)xa0.w;
            p0.e[4] = (__bf16)xb0.x; p0.e[5] = (__bf16)xb0.y;
            p0.e[6] = (__bf16)xb0.z; p0.e[7] = (__bf16)xb0.w;
            p1.e[0] = (__bf16)xa1.x; p1.e[1] = (__bf16)xa1.y;
            p1.e[2] = (__bf16)xa1.z; p1.e[3] = (__bf16)xa1.w;
            p1.e[4] = (__bf16)xb1.x; p1.e[5] = (__bf16)xb1.y;
            p1.e[6] = (__bf16)xb1.z; p1.e[7] = (__bf16)xb1.w;
            #pragma unroll
            for (int tn = 0; tn < 9; ++tn) {
                int off = (((tn << 2) + tk) * 64 + l) * 8;
                bf16x8 bh = *reinterpret_cast<const bf16x8*>(&B0[off]);
                bf16x8 bl = *reinterpret_cast<const bf16x8*>(&B1[off]);
                acc[0][tn] = __builtin_amdgcn_mfma_f32_16x16x32_bf16(p0.b, bh, acc[0][tn], 0, 0, 0);
                acc[0][tn] = __builtin_amdgcn_mfma_f32_16x16x32_bf16(p0.b, bl, acc[0][tn], 0, 0, 0);
                acc[1][tn] = __builtin_amdgcn_mfma_f32_16x16x32_bf16(p1.b, bh, acc[1][tn], 0, 0, 0);
                acc[1][tn] = __builtin_amdgcn_mfma_f32_16x16x32_bf16(p1.b, bl, acc[1][tn], 0, 0, 0);
            }
        }

        __syncthreads();   // all B reads done; reuse B0 as transpose scratch

        const int g = l >> 4;
        unsigned short* hs = B0 + w * 2048;     // wave-private 16x128 bf16
        __bf16* hsb = reinterpret_cast<__bf16*>(hs);
        #pragma unroll
        for (int mt = 0; mt < 2; ++mt) {
            const int rowbase = blockIdx.x * 128 + mt * 64 + w * 16;
            #pragma unroll
            for (int tn = 0; tn < 8; ++tn) {
                #pragma unroll
                for (int r = 0; r < 4; ++r)
                    hsb[((g << 2) + r) * 128 + (tn << 4) + (l & 15)] =
                        (__bf16)acc[mt][tn][r];
            }
            if ((l & 15) < 8) {
                int j = l & 15, q = j >> 1, s = j & 1;
                float* dp = s ? adst : asrc;
                #pragma unroll
                for (int r = 0; r < 4; ++r) {
                    int rr = rowbase + (g << 2) + r;
                    if (rr < NN) dp[rr * 4 + q] = acc[mt][8][r];
                }
            }
            __syncthreads();
            if (rowbase < NN) {
                const uint4* sp = (const uint4*)hs;
                uint4* dp = (uint4*)(h16 + (size_t)rowbase * 128);
                #pragma unroll
                for (int i = 0; i < 4; ++i) dp[i * 64 + l] = sp[i * 64 + l];
            }
            __syncthreads();
        }
        return;
    }

    // ---- kb_build (LDS aliased into B0) ----
    int* lenS = (int*)B0;            // [256]
    int* hist = lenS + NRANGE;       // [512]
    int* cur  = hist + 512;          // [391]
    const int r = blockIdx.x - GEMM_BLK;
    const int t = tid;

    lenS[t] = rangeRes[t * 16];
    __syncthreads();
    for (int off = 1; off < NRANGE; off <<= 1) {
        int v = (t >= off) ? lenS[t - off] : 0;
        __syncthreads();
        lenS[t] += v;
        __syncthreads();
    }
    const int rangeOff = r ? lenS[r - 1] : 0;
    const int n = lenS[r] - rangeOff;
    const int lo = r * RDST;
    const int nd = min(RDST, NN - lo);

    hist[t] = 0; hist[t + 256] = 0;
    __syncthreads();
    const unsigned* bp = bins + (size_t)r * CAP;
    for (int i = t; i < n; i += 256)
        atomicAdd(&hist[bp[i] >> 17], 1);
    __syncthreads();
    for (int off = 1; off < 512; off <<= 1) {
        int i0 = t, i1 = t + 256;
        int v0 = (i0 >= off) ? hist[i0 - off] : 0;
        int v1 = (i1 >= off) ? hist[i1 - off] : 0;
        __syncthreads();
        hist[i0] += v0; hist[i1] += v1;
        __syncthreads();
    }
    for (int b = t; b < RDST; b += 256) cur[b] = b ? hist[b - 1] : 0;
    __syncthreads();
    for (int i = t; i < n; i += 256) {
        unsigned v = bp[i];
        int pos = atomicAdd(&cur[v >> 17], 1);
        csr_src[rangeOff + pos] = (int)(v & 0x1FFFFu);
    }
    __syncthreads();
    for (int b = t; b < nd; b += 256) cursor[lo + b] = rangeOff + cur[b];
}

// ---------------------------------------------------------------------------
// k4: one wave per dst node; four 16-lane groups, software-pipelined 4-deep.
// ---------------------------------------------------------------------------
__global__ __launch_bounds__(256) void k4_agg(
    const int* __restrict__ cursor, const int* __restrict__ csr_src,
    const float* __restrict__ asrc, const float* __restrict__ adst,
    const unsigned short* __restrict__ h16, float* __restrict__ out)
{
    int wid = (blockIdx.x * 256 + threadIdx.x) >> 6;
    if (wid >= NN) return;
    int l = threadIdx.x & 63;
    int g = l >> 4;           // edge subgroup 0..3
    int cidx = l & 15;        // col granule: cols cidx*8 .. cidx*8+7
    int head = cidx >> 2;

    int end = cursor[wid];
    int beg = wid ? cursor[wid - 1] : 0;

    float ad = adst[(size_t)wid * 4 + head];

    float acc[8];
    #pragma unroll
    for (int c = 0; c < 8; ++c) acc[c] = 0.f;
    float sum = 0.f;

    int i = beg + g;
    if (i < end) {
        const int last = end - 1;
        int s0 = csr_src[i];
        int s1 = csr_src[min(i + 4,  last)];
        int s2 = csr_src[min(i + 8,  last)];
        int s3 = csr_src[min(i + 12, last)];
        do {
            int i2 = i + 16;
            int t0 = csr_src[min(i2,      last)];
            int t1 = csr_src[min(i2 + 4,  last)];
            int t2 = csr_src[min(i2 + 8,  last)];
            int t3 = csr_src[min(i2 + 12, last)];

            float a0 = asrc[(size_t)s0 * 4 + head];
            uint4 h0 = *(const uint4*)(h16 + (size_t)s0 * 128 + cidx * 8);
            float a1 = asrc[(size_t)s1 * 4 + head];
            uint4 h1 = *(const uint4*)(h16 + (size_t)s1 * 128 + cidx * 8);
            float a2 = asrc[(size_t)s2 * 4 + head];
            uint4 h2 = *(const uint4*)(h16 + (size_t)s2 * 128 + cidx * 8);
            float a3 = asrc[(size_t)s3 * 4 + head];
            uint4 h3 = *(const uint4*)(h16 + (size_t)s3 * 128 + cidx * 8);

            float sc0 = a0 + ad; sc0 = sc0 >= 0.f ? sc0 : 0.2f * sc0;
            float sc1 = a1 + ad; sc1 = sc1 >= 0.f ? sc1 : 0.2f * sc1;
            float sc2 = a2 + ad; sc2 = sc2 >= 0.f ? sc2 : 0.2f * sc2;
            float sc3 = a3 + ad; sc3 = sc3 >= 0.f ? sc3 : 0.2f * sc3;
            float w0 = __expf(sc0);
            float w1 = (i + 4  <= last) ? __expf(sc1) : 0.f;
            float w2 = (i + 8  <= last) ? __expf(sc2) : 0.f;
            float w3 = (i + 12 <= last) ? __expf(sc3) : 0.f;
            sum += (w0 + w1) + (w2 + w3);

            acc[0] = fmaf(w0, __uint_as_float(h0.x << 16),         acc[0]);
            acc[1] = fmaf(w0, __uint_as_float(h0.x & 0xffff0000u), acc[1]);
            acc[2] = fmaf(w0, __uint_as_float(h0.y << 16),         acc[2]);
            acc[3] = fmaf(w0, __uint_as_float(h0.y & 0xffff0000u), acc[3]);
            acc[4] = fmaf(w0, __uint_as_float(h0.z << 16),         acc[4]);
            acc[5] = fmaf(w0, __uint_as_float(h0.z & 0xffff0000u), acc[5]);
            acc[6] = fmaf(w0, __uint_as_float(h0.w << 16),         acc[6]);
            acc[7] = fmaf(w0, __uint_as_float(h0.w & 0xffff0000u), acc[7]);

            acc[0] = fmaf(w1, __uint_as_float(h1.x << 16),         acc[0]);
            acc[1] = fmaf(w1, __uint_as_float(h1.x & 0xffff0000u), acc[1]);
            acc[2] = fmaf(w1, __uint_as_float(h1.y << 16),         acc[2]);
            acc[3] = fmaf(w1, __uint_as_float(h1.y & 0xffff0000u), acc[3]);
            acc[4] = fmaf(w1, __uint_as_float(h1.z << 16),         acc[4]);
            acc[5] = fmaf(w1, __uint_as_float(h1.z & 0xffff0000u), acc[5]);
            acc[6] = fmaf(w1, __uint_as_float(h1.w << 16),         acc[6]);
            acc[7] = fmaf(w1, __uint_as_float(h1.w & 0xffff0000u), acc[7]);

            acc[0] = fmaf(w2, __uint_as_float(h2.x << 16),         acc[0]);
            acc[1] = fmaf(w2, __uint_as_float(h2.x & 0xffff0000u), acc[1]);
            acc[2] = fmaf(w2, __uint_as_float(h2.y << 16),         acc[2]);
            acc[3] = fmaf(w2, __uint_as_float(h2.y & 0xffff0000u), acc[3]);
            acc[4] = fmaf(w2, __uint_as_float(h2.z << 16),         acc[4]);
            acc[5] = fmaf(w2, __uint_as_float(h2.z & 0xffff0000u), acc[5]);
            acc[6] = fmaf(w2, __uint_as_float(h2.w << 16),         acc[6]);
            acc[7] = fmaf(w2, __uint_as_float(h2.w & 0xffff0000u), acc[7]);

            acc[0] = fmaf(w3, __uint_as_float(h3.x << 16),         acc[0]);
            acc[1] = fmaf(w3, __uint_as_float(h3.x & 0xffff0000u), acc[1]);
            acc[2] = fmaf(w3, __uint_as_float(h3.y << 16),         acc[2]);
            acc[3] = fmaf(w3, __uint_as_float(h3.y & 0xffff0000u), acc[3]);
            acc[4] = fmaf(w3, __uint_as_float(h3.z << 16),         acc[4]);
            acc[5] = fmaf(w3, __uint_as_float(h3.z & 0xffff0000u), acc[5]);
            acc[6] = fmaf(w3, __uint_as_float(h3.w << 16),         acc[6]);
            acc[7] = fmaf(w3, __uint_as_float(h3.w & 0xffff0000u), acc[7]);

            s0 = t0; s1 = t1; s2 = t2; s3 = t3; i = i2;
        } while (i < end);
    }

    #pragma unroll
    for (int c = 0; c < 8; ++c) {
        acc[c] += __shfl_xor(acc[c], 16);
        acc[c] += __shfl_xor(acc[c], 32);
    }
    sum += __shfl_xor(sum, 16);
    sum += __shfl_xor(sum, 32);

    if (g == 0) {
        float rs = 1.0f / (sum + 1e-16f);
        f32x4* ob = (f32x4*)(out + (size_t)wid * 128 + cidx * 8);
        f32x4 v0 = {acc[0] * rs, acc[1] * rs, acc[2] * rs, acc[3] * rs};
        f32x4 v1 = {acc[4] * rs, acc[5] * rs, acc[6] * rs, acc[7] * rs};
        __builtin_nontemporal_store(v0, ob);
        __builtin_nontemporal_store(v1, ob + 1);
    }
}

// ---------------------------------------------------------------------------
extern "C" void kernel_launch(void* const* d_in, const int* in_sizes, int n_in,
                              void* d_out, int out_size, void* d_ws, size_t ws_size,
                              hipStream_t stream)
{
    const float* X  = (const float*)d_in[0];
    const int*   ei = (const int*)d_in[1];
    const float* W  = (const float*)d_in[2];
    const float* a  = (const float*)d_in[3];
    float* out = (float*)d_out;

    // workspace layout (4-byte elements), total ~43 MB
    unsigned short* h16 = (unsigned short*)d_ws;          // NN*128 bf16 = 6.4M elems
    float* asrc     = (float*)d_ws + 6400000;             // NN*4
    float* adst     = asrc + 400000;                      // NN*4
    int*   csr_src  = (int*)(adst + 400000);              // NE
    int*   cursor   = csr_src + 1600000;                  // NN
    int*   rangeRes = cursor + 100000;                    // NRANGE*16 (padded)
    uint4* B0g      = (uint4*)(rangeRes + NRANGE * 16);   // 2304 uint4 = 36 KB
    uint4* B1g      = B0g + 2304;                         // 36 KB
    unsigned* bins  = (unsigned*)(B1g + 2304);            // NRANGE*CAP = 7 MB

    hipMemsetAsync(rangeRes, 0, NRANGE * 16 * sizeof(int), stream);

    kA_prep_bin<<<1 + NCHA, 256, 0, stream>>>(W, a, B0g, B1g, ei, rangeRes, bins);
    kB_gemm_build<<<GEMM_BLK + NRANGE, 256, 0, stream>>>(X, B0g, B1g, h16,
                                                         asrc, adst, rangeRes,
                                                         bins, csr_src, cursor);
    k4_agg<<<(NN * 64 + 255) / 256, 256, 0, stream>>>(cursor, csr_src,
                                                      asrc, adst, h16, out);
}

// Round 17
// 137.614 us; speedup vs baseline: 1.0547x; 1.0082x over previous
//
#include <hip/hip_runtime.h>

#define NN 100000
#define NE 1600000

#define NRANGE 256
#define RDST 391                          // ceil(NN/NRANGE); 256*391 = 100096
#define CAP 6800                          // per-range bin capacity (mean 6256, ~7 sigma)
#define EPB_A 4096
#define NCHA ((NE + EPB_A - 1) / EPB_A)   // 391 chunks
#define GEMM_BLK 782                      // ceil(NN/128)

typedef __attribute__((ext_vector_type(8))) __bf16 bf16x8;
typedef __attribute__((ext_vector_type(4))) float  f32x4;

static __device__ __forceinline__ unsigned f2bf(float f) {
    unsigned u = __float_as_uint(f);
    return (u + 0x7fffu + ((u >> 16) & 1u)) >> 16;   // RNE
}
static __device__ __forceinline__ float bf2f(unsigned b) {
    return __uint_as_float(b << 16);
}

union PkA { unsigned u[4]; bf16x8 b; __bf16 e[8]; };

// ---------------------------------------------------------------------------
// kA: fused independent phases.
//   block 0       : B-panel prep ([W|Wa|0] -> split-bf16 fragment order)
//   blocks 1..391 : ka_bin chunk binning (4096 edges/chunk)
// ---------------------------------------------------------------------------
__global__ __launch_bounds__(256) void kA_prep_bin(
    const float* __restrict__ W, const float* __restrict__ a,
    uint4* __restrict__ B0g, uint4* __restrict__ B1g,
    const int* __restrict__ ei, int* __restrict__ rangeRes,
    unsigned* __restrict__ bins)
{
    __shared__ float sWa[1024];
    __shared__ int cnt[NRANGE], base[NRANGE], cur[NRANGE];
    const int t = threadIdx.x;

    if (blockIdx.x == 0) {
        // ---- kprep ----
        for (int e = t; e < 1024; e += 256) {
            int k = e >> 3, j = e & 7, q = j >> 1, s = j & 1;
            float sum = 0.f;
            #pragma unroll
            for (int c = 0; c < 32; ++c)
                sum = fmaf(W[k * 128 + q * 32 + c], a[q * 64 + s * 32 + c], sum);
            sWa[e] = sum;
        }
        __syncthreads();
        #pragma unroll
        for (int it = 0; it < 9; ++it) {
            int f  = it * 256 + t;         // 0..2303
            int l  = f & 63;
            int tk = (f >> 6) & 3;
            int tn = f >> 8;
            int col = tn * 16 + (l & 15);
            int kk  = tk * 32 + ((l >> 4) << 3);
            unsigned hb[8], lb[8];
            #pragma unroll
            for (int j = 0; j < 8; ++j) {
                float w;
                if (col < 128)       w = W[(kk + j) * 128 + col];
                else if (col < 136)  w = sWa[(kk + j) * 8 + (col - 128)];
                else                 w = 0.f;
                hb[j] = f2bf(w);
                lb[j] = f2bf(w - bf2f(hb[j]));
            }
            B0g[f] = make_uint4(hb[0] | (hb[1] << 16), hb[2] | (hb[3] << 16),
                                hb[4] | (hb[5] << 16), hb[6] | (hb[7] << 16));
            B1g[f] = make_uint4(lb[0] | (lb[1] << 16), lb[2] | (lb[3] << 16),
                                lb[4] | (lb[5] << 16), lb[6] | (lb[7] << 16));
        }
        return;
    }

    // ---- ka_bin ----
    const int c  = blockIdx.x - 1;
    const int b0 = c * EPB_A;
    const int b1 = min(NE, b0 + EPB_A);

    cnt[t] = 0;
    __syncthreads();
    for (int i = b0 + t; i < b1; i += 256)
        atomicAdd(&cnt[ei[NE + i] / RDST], 1);
    __syncthreads();
    base[t] = atomicAdd(&rangeRes[t * 16], cnt[t]) + t * CAP;
    cur[t] = 0;
    __syncthreads();
    for (int i = b0 + t; i < b1; i += 256) {
        int s = ei[i], d = ei[NE + i];
        int r = d / RDST;
        unsigned dloc = (unsigned)(d - r * RDST);
        int off = atomicAdd(&cur[r], 1);
        bins[base[r] + off] = (dloc << 17) | (unsigned)s;
    }
}

// ---------------------------------------------------------------------------
// kB: fused independent phases.
//   blocks 0..781    : k1 GEMM, 128 rows/block, asymmetric split precision:
//                      hi-pass for all 9 N-tiles; lo-correction ONLY for the
//                      alpha tile (tn=8, feeds exp). h-tiles' lo term is
//                      below the bf16-storage quantum -> dropped.
//                      LDS 40 KB (36 hi + 4 lo) -> higher occupancy,
//                      LDS reads/wave 72 -> 40, MFMA/wave 144 -> 80.
//   blocks 782..1037 : kb_build (LDS aliased into B0 staging buffer)
// ---------------------------------------------------------------------------
__global__ __launch_bounds__(256) void kB_gemm_build(
    const float* __restrict__ X, const uint4* __restrict__ B0g,
    const uint4* __restrict__ B1g, unsigned short* __restrict__ h16,
    float* __restrict__ asrc, float* __restrict__ adst,
    const int* __restrict__ rangeRes, const unsigned* __restrict__ bins,
    int* __restrict__ csr_src, int* __restrict__ cursor)
{
    __shared__ unsigned short B0[9 * 4 * 64 * 8];   // 36 KB  hi (all tiles)
    __shared__ unsigned short B1s[4 * 64 * 8];      //  4 KB  lo (tn=8 only)
    const int tid = threadIdx.x;

    if (blockIdx.x < GEMM_BLK) {
        // ---- stage B: full hi panel + lo panel for tn=8 only ----
        {
            uint4* s0 = (uint4*)B0;
            #pragma unroll
            for (int it = 0; it < 9; ++it)
                s0[it * 256 + tid] = B0g[it * 256 + tid];
            ((uint4*)B1s)[tid] = B1g[8 * 256 + tid];
        }
        __syncthreads();

        const int w = tid >> 6;
        const int l = tid & 63;
        const int r0 = blockIdx.x * 128 + w * 16 + (l & 15);  // mt=0 A row
        const float* xr0 = X + (size_t)min(r0,      NN - 1) * 128 + ((l >> 4) << 3);
        const float* xr1 = X + (size_t)min(r0 + 64, NN - 1) * 128 + ((l >> 4) << 3);

        f32x4 acc[2][9];
        #pragma unroll
        for (int m = 0; m < 2; ++m)
            #pragma unroll
            for (int t = 0; t < 9; ++t) acc[m][t] = (f32x4){0.f, 0.f, 0.f, 0.f};

        #pragma unroll
        for (int tk = 0; tk < 4; ++tk) {
            float4 xa0 = *(const float4*)(xr0 + tk * 32);
            float4 xb0 = *(const float4*)(xr0 + tk * 32 + 4);
            float4 xa1 = *(const float4*)(xr1 + tk * 32);
            float4 xb1 = *(const float4*)(xr1 + tk * 32 + 4);
            PkA p0, p1;
            p0.e[0] = (__bf16)xa0.x; p0.e[1] = (__bf16)xa0.y;
            p0.e[2] = (__bf16)xa0.z; p0.e[3] = (__bf16)xa0.w;
            p0.e[4] = (__bf16)xb0.x; p0.e[5] = (__bf16)xb0.y;
            p0.e[6] = (__bf16)xb0.z; p0.e[7] = (__bf16)xb0.w;
            p1.e[0] = (__bf16)xa1.x; p1.e[1] = (__bf16)xa1.y;
            p1.e[2] = (__bf16)xa1.z; p1.e[3] = (__bf16)xa1.w;
            p1.e[4] = (__bf16)xb1.x; p1.e[5] = (__bf16)xb1.y;
            p1.e[6] = (__bf16)xb1.z; p1.e[7] = (__bf16)xb1.w;
            #pragma unroll
            for (int tn = 0; tn < 9; ++tn) {
                int off = (((tn << 2) + tk) * 64 + l) * 8;
                bf16x8 bh = *reinterpret_cast<const bf16x8*>(&B0[off]);
                acc[0][tn] = __builtin_amdgcn_mfma_f32_16x16x32_bf16(p0.b, bh, acc[0][tn], 0, 0, 0);
                acc[1][tn] = __builtin_amdgcn_mfma_f32_16x16x32_bf16(p1.b, bh, acc[1][tn], 0, 0, 0);
                if (tn == 8) {
                    bf16x8 bl = *reinterpret_cast<const bf16x8*>(&B1s[(tk * 64 + l) * 8]);
                    acc[0][8] = __builtin_amdgcn_mfma_f32_16x16x32_bf16(p0.b, bl, acc[0][8], 0, 0, 0);
                    acc[1][8] = __builtin_amdgcn_mfma_f32_16x16x32_bf16(p1.b, bl, acc[1][8], 0, 0, 0);
                }
            }
        }

        __syncthreads();   // all B reads done; reuse B0 as transpose scratch

        const int g = l >> 4;
        unsigned short* hs = B0 + w * 2048;     // wave-private 16x128 bf16
        __bf16* hsb = reinterpret_cast<__bf16*>(hs);
        #pragma unroll
        for (int mt = 0; mt < 2; ++mt) {
            const int rowbase = blockIdx.x * 128 + mt * 64 + w * 16;
            #pragma unroll
            for (int tn = 0; tn < 8; ++tn) {
                #pragma unroll
                for (int r = 0; r < 4; ++r)
                    hsb[((g << 2) + r) * 128 + (tn << 4) + (l & 15)] =
                        (__bf16)acc[mt][tn][r];
            }
            if ((l & 15) < 8) {
                int j = l & 15, q = j >> 1, s = j & 1;
                float* dp = s ? adst : asrc;
                #pragma unroll
                for (int r = 0; r < 4; ++r) {
                    int rr = rowbase + (g << 2) + r;
                    if (rr < NN) dp[rr * 4 + q] = acc[mt][8][r];
                }
            }
            __syncthreads();
            if (rowbase < NN) {
                const uint4* sp = (const uint4*)hs;
                uint4* dp = (uint4*)(h16 + (size_t)rowbase * 128);
                #pragma unroll
                for (int i = 0; i < 4; ++i) dp[i * 64 + l] = sp[i * 64 + l];
            }
            __syncthreads();
        }
        return;
    }

    // ---- kb_build (LDS aliased into B0) ----
    int* lenS = (int*)B0;            // [256]
    int* hist = lenS + NRANGE;       // [512]
    int* cur  = hist + 512;          // [391]
    const int r = blockIdx.x - GEMM_BLK;
    const int t = tid;

    lenS[t] = rangeRes[t * 16];
    __syncthreads();
    for (int off = 1; off < NRANGE; off <<= 1) {
        int v = (t >= off) ? lenS[t - off] : 0;
        __syncthreads();
        lenS[t] += v;
        __syncthreads();
    }
    const int rangeOff = r ? lenS[r - 1] : 0;
    const int n = lenS[r] - rangeOff;
    const int lo = r * RDST;
    const int nd = min(RDST, NN - lo);

    hist[t] = 0; hist[t + 256] = 0;
    __syncthreads();
    const unsigned* bp = bins + (size_t)r * CAP;
    for (int i = t; i < n; i += 256)
        atomicAdd(&hist[bp[i] >> 17], 1);
    __syncthreads();
    for (int off = 1; off < 512; off <<= 1) {
        int i0 = t, i1 = t + 256;
        int v0 = (i0 >= off) ? hist[i0 - off] : 0;
        int v1 = (i1 >= off) ? hist[i1 - off] : 0;
        __syncthreads();
        hist[i0] += v0; hist[i1] += v1;
        __syncthreads();
    }
    for (int b = t; b < RDST; b += 256) cur[b] = b ? hist[b - 1] : 0;
    __syncthreads();
    for (int i = t; i < n; i += 256) {
        unsigned v = bp[i];
        int pos = atomicAdd(&cur[v >> 17], 1);
        csr_src[rangeOff + pos] = (int)(v & 0x1FFFFu);
    }
    __syncthreads();
    for (int b = t; b < nd; b += 256) cursor[lo + b] = rangeOff + cur[b];
}

// ---------------------------------------------------------------------------
// k4: one wave per dst node; four 16-lane groups, software-pipelined 4-deep.
// ---------------------------------------------------------------------------
__global__ __launch_bounds__(256) void k4_agg(
    const int* __restrict__ cursor, const int* __restrict__ csr_src,
    const float* __restrict__ asrc, const float* __restrict__ adst,
    const unsigned short* __restrict__ h16, float* __restrict__ out)
{
    int wid = (blockIdx.x * 256 + threadIdx.x) >> 6;
    if (wid >= NN) return;
    int l = threadIdx.x & 63;
    int g = l >> 4;           // edge subgroup 0..3
    int cidx = l & 15;        // col granule: cols cidx*8 .. cidx*8+7
    int head = cidx >> 2;

    int end = cursor[wid];
    int beg = wid ? cursor[wid - 1] : 0;

    float ad = adst[(size_t)wid * 4 + head];

    float acc[8];
    #pragma unroll
    for (int c = 0; c < 8; ++c) acc[c] = 0.f;
    float sum = 0.f;

    int i = beg + g;
    if (i < end) {
        const int last = end - 1;
        int s0 = csr_src[i];
        int s1 = csr_src[min(i + 4,  last)];
        int s2 = csr_src[min(i + 8,  last)];
        int s3 = csr_src[min(i + 12, last)];
        do {
            int i2 = i + 16;
            int t0 = csr_src[min(i2,      last)];
            int t1 = csr_src[min(i2 + 4,  last)];
            int t2 = csr_src[min(i2 + 8,  last)];
            int t3 = csr_src[min(i2 + 12, last)];

            float a0 = asrc[(size_t)s0 * 4 + head];
            uint4 h0 = *(const uint4*)(h16 + (size_t)s0 * 128 + cidx * 8);
            float a1 = asrc[(size_t)s1 * 4 + head];
            uint4 h1 = *(const uint4*)(h16 + (size_t)s1 * 128 + cidx * 8);
            float a2 = asrc[(size_t)s2 * 4 + head];
            uint4 h2 = *(const uint4*)(h16 + (size_t)s2 * 128 + cidx * 8);
            float a3 = asrc[(size_t)s3 * 4 + head];
            uint4 h3 = *(const uint4*)(h16 + (size_t)s3 * 128 + cidx * 8);

            float sc0 = a0 + ad; sc0 = sc0 >= 0.f ? sc0 : 0.2f * sc0;
            float sc1 = a1 + ad; sc1 = sc1 >= 0.f ? sc1 : 0.2f * sc1;
            float sc2 = a2 + ad; sc2 = sc2 >= 0.f ? sc2 : 0.2f * sc2;
            float sc3 = a3 + ad; sc3 = sc3 >= 0.f ? sc3 : 0.2f * sc3;
            float w0 = __expf(sc0);
            float w1 = (i + 4  <= last) ? __expf(sc1) : 0.f;
            float w2 = (i + 8  <= last) ? __expf(sc2) : 0.f;
            float w3 = (i + 12 <= last) ? __expf(sc3) : 0.f;
            sum += (w0 + w1) + (w2 + w3);

            acc[0] = fmaf(w0, __uint_as_float(h0.x << 16),         acc[0]);
            acc[1] = fmaf(w0, __uint_as_float(h0.x & 0xffff0000u), acc[1]);
            acc[2] = fmaf(w0, __uint_as_float(h0.y << 16),         acc[2]);
            acc[3] = fmaf(w0, __uint_as_float(h0.y & 0xffff0000u), acc[3]);
            acc[4] = fmaf(w0, __uint_as_float(h0.z << 16),         acc[4]);
            acc[5] = fmaf(w0, __uint_as_float(h0.z & 0xffff0000u), acc[5]);
            acc[6] = fmaf(w0, __uint_as_float(h0.w << 16),         acc[6]);
            acc[7] = fmaf(w0, __uint_as_float(h0.w & 0xffff0000u), acc[7]);

            acc[0] = fmaf(w1, __uint_as_float(h1.x << 16),         acc[0]);
            acc[1] = fmaf(w1, __uint_as_float(h1.x & 0xffff0000u), acc[1]);
            acc[2] = fmaf(w1, __uint_as_float(h1.y << 16),         acc[2]);
            acc[3] = fmaf(w1, __uint_as_float(h1.y & 0xffff0000u), acc[3]);
            acc[4] = fmaf(w1, __uint_as_float(h1.z << 16),         acc[4]);
            acc[5] = fmaf(w1, __uint_as_float(h1.z & 0xffff0000u), acc[5]);
            acc[6] = fmaf(w1, __uint_as_float(h1.w << 16),         acc[6]);
            acc[7] = fmaf(w1, __uint_as_float(h1.w & 0xffff0000u), acc[7]);

            acc[0] = fmaf(w2, __uint_as_float(h2.x << 16),         acc[0]);
            acc[1] = fmaf(w2, __uint_as_float(h2.x & 0xffff0000u), acc[1]);
            acc[2] = fmaf(w2, __uint_as_float(h2.y << 16),         acc[2]);
            acc[3] = fmaf(w2, __uint_as_float(h2.y & 0xffff0000u), acc[3]);
            acc[4] = fmaf(w2, __uint_as_float(h2.z << 16),         acc[4]);
            acc[5] = fmaf(w2, __uint_as_float(h2.z & 0xffff0000u), acc[5]);
            acc[6] = fmaf(w2, __uint_as_float(h2.w << 16),         acc[6]);
            acc[7] = fmaf(w2, __uint_as_float(h2.w & 0xffff0000u), acc[7]);

            acc[0] = fmaf(w3, __uint_as_float(h3.x << 16),         acc[0]);
            acc[1] = fmaf(w3, __uint_as_float(h3.x & 0xffff0000u), acc[1]);
            acc[2] = fmaf(w3, __uint_as_float(h3.y << 16),         acc[2]);
            acc[3] = fmaf(w3, __uint_as_float(h3.y & 0xffff0000u), acc[3]);
            acc[4] = fmaf(w3, __uint_as_float(h3.z << 16),         acc[4]);
            acc[5] = fmaf(w3, __uint_as_float(h3.z & 0xffff0000u), acc[5]);
            acc[6] = fmaf(w3, __uint_as_float(h3.w << 16),         acc[6]);
            acc[7] = fmaf(w3, __uint_as_float(h3.w & 0xffff0000u), acc[7]);

            s0 = t0; s1 = t1; s2 = t2; s3 = t3; i = i2;
        } while (i < end);
    }

    #pragma unroll
    for (int c = 0; c < 8; ++c) {
        acc[c] += __shfl_xor(acc[c], 16);
        acc[c] += __shfl_xor(acc[c], 32);
    }
    sum += __shfl_xor(sum, 16);
    sum += __shfl_xor(sum, 32);

    if (g == 0) {
        float rs = 1.0f / (sum + 1e-16f);
        f32x4* ob = (f32x4*)(out + (size_t)wid * 128 + cidx * 8);
        f32x4 v0 = {acc[0] * rs, acc[1] * rs, acc[2] * rs, acc[3] * rs};
        f32x4 v1 = {acc[4] * rs, acc[5] * rs, acc[6] * rs, acc[7] * rs};
        __builtin_nontemporal_store(v0, ob);
        __builtin_nontemporal_store(v1, ob + 1);
    }
}

// ---------------------------------------------------------------------------
extern "C" void kernel_launch(void* const* d_in, const int* in_sizes, int n_in,
                              void* d_out, int out_size, void* d_ws, size_t ws_size,
                              hipStream_t stream)
{
    const float* X  = (const float*)d_in[0];
    const int*   ei = (const int*)d_in[1];
    const float* W  = (const float*)d_in[2];
    const float* a  = (const float*)d_in[3];
    float* out = (float*)d_out;

    // workspace layout (4-byte elements), total ~43 MB
    unsigned short* h16 = (unsigned short*)d_ws;          // NN*128 bf16 = 6.4M elems
    float* asrc     = (float*)d_ws + 6400000;             // NN*4
    float* adst     = asrc + 400000;                      // NN*4
    int*   csr_src  = (int*)(adst + 400000);              // NE
    int*   cursor   = csr_src + 1600000;                  // NN
    int*   rangeRes = cursor + 100000;                    // NRANGE*16 (padded)
    uint4* B0g      = (uint4*)(rangeRes + NRANGE * 16);   // 2304 uint4 = 36 KB
    uint4* B1g      = B0g + 2304;                         // 36 KB
    unsigned* bins  = (unsigned*)(B1g + 2304);            // NRANGE*CAP = 7 MB

    hipMemsetAsync(rangeRes, 0, NRANGE * 16 * sizeof(int), stream);

    kA_prep_bin<<<1 + NCHA, 256, 0, stream>>>(W, a, B0g, B1g, ei, rangeRes, bins);
    kB_gemm_build<<<GEMM_BLK + NRANGE, 256, 0, stream>>>(X, B0g, B1g, h16,
                                                         asrc, adst, rangeRes,
                                                         bins, csr_src, cursor);
    k4_agg<<<(NN * 64 + 255) / 256, 256, 0, stream>>>(cursor, csr_src,
                                                      asrc, adst, h16, out);
}